// Round 2
// baseline (322.269 us; speedup 1.0000x reference)
//
#include <hip/hip_runtime.h>
#include <cstddef>
#include <cstdint>

// ---------------------------------------------------------------------------
// MILModel7 forward, fp32.
// Key exact simplification: softmax over axis=1 of (s_i + s_j + Wb) makes the
// j-dependent terms cancel -> scores = softmax(s, axis=n). No n x n matrix.
// Phase A (milA): per-32-row fused chain:
//   vo1 = relu(vfeat @ vfc_w^T + vfc_b)          K=512 -> 128
//   ax  = relu(afeat @ afc_w^T + afc_b)          K=128 -> 128
//   h   = tanh(vo1 @ am_v_w^T + am_v_b + ax @ am_a_w^T + am_a_b)
//   att = sigmoid(h . am_o_w + am_o_b)
//   ffeat = att*ax + vo1                          (stored to ws)
//   f_v = relu(ffeat @ V_w^T + V_b);  s = f_v . W_w   (stored to ws)
// Phase B (milB): per-batch softmax(s) -> scores; zfeat = sum_n scores*ffeat;
//   logits = zfeat @ cls_w^T + cls_b.
// ---------------------------------------------------------------------------

__device__ __forceinline__ void fma16(float (&acc)[4][4], const float4 a, const float4 b) {
    const float av[4] = {a.x, a.y, a.z, a.w};
    const float bv[4] = {b.x, b.y, b.z, b.w};
#pragma unroll
    for (int i = 0; i < 4; i++)
#pragma unroll
        for (int j = 0; j < 4; j++)
            acc[i][j] += av[i] * bv[j];
}

__global__ __launch_bounds__(256, 2)
void milA(const float* __restrict__ vfeat, const float* __restrict__ afeat,
          const float* __restrict__ vfc_w, const float* __restrict__ vfc_b,
          const float* __restrict__ afc_w, const float* __restrict__ afc_b,
          const float* __restrict__ am_v_w, const float* __restrict__ am_v_b,
          const float* __restrict__ am_a_w, const float* __restrict__ am_a_b,
          const float* __restrict__ am_o_w, const float* __restrict__ am_o_b,
          const float* __restrict__ V_w, const float* __restrict__ V_b,
          const float* __restrict__ W_w,
          float* __restrict__ ffeat_out, float* __restrict__ s_out)
{
    __shared__ float Bs[32][128];     // weight tile, transposed [k][o]   16 KB
    __shared__ float As[32][36];      // input tile, transposed [k][row]  4.6 KB
    __shared__ float vo1s[128][36];   // vo1, transposed [k][row]         18.4 KB
    __shared__ float axs[128][36];    // ax,  transposed [k][row]         18.4 KB
    __shared__ float atts[32];

    const int tid = threadIdx.x;
    const int r0  = blockIdx.x * 32;          // global row base (b*2048+n flat)
    const int ty  = tid >> 5;                 // 0..7  row-group (4 rows each)
    const int tx  = tid & 31;                 // 0..31 col-group (4 cols each)

    // staging roles
    const int srow = tid >> 3, skq = tid & 7;         // As: row, k-quad
    const int so   = tid >> 1, skh = (tid & 1) * 16;  // Bs: out-row, k-half

    float acc[4][4];

    // ---------------- GEMM1: vo1, K = 512 ----------------
#pragma unroll
    for (int i = 0; i < 4; i++)
#pragma unroll
        for (int j = 0; j < 4; j++) acc[i][j] = 0.f;

    for (int k0 = 0; k0 < 512; k0 += 32) {
        float4 av = *(const float4*)(vfeat + (size_t)(r0 + srow) * 512 + k0 + skq * 4);
        const float* wp = vfc_w + (size_t)so * 512 + k0 + skh;
        float4 wv[4];
#pragma unroll
        for (int q = 0; q < 4; q++) wv[q] = *(const float4*)(wp + q * 4);

        As[skq * 4 + 0][srow] = av.x; As[skq * 4 + 1][srow] = av.y;
        As[skq * 4 + 2][srow] = av.z; As[skq * 4 + 3][srow] = av.w;
#pragma unroll
        for (int q = 0; q < 4; q++) {
            Bs[skh + q * 4 + 0][so] = wv[q].x;
            Bs[skh + q * 4 + 1][so] = wv[q].y;
            Bs[skh + q * 4 + 2][so] = wv[q].z;
            Bs[skh + q * 4 + 3][so] = wv[q].w;
        }
        __syncthreads();
#pragma unroll
        for (int kk = 0; kk < 32; kk++) {
            float4 a = *(const float4*)&As[kk][ty * 4];
            float4 b = *(const float4*)&Bs[kk][tx * 4];
            fma16(acc, a, b);
        }
        __syncthreads();
    }
    // epilogue: bias + relu -> vo1s[col][row]
#pragma unroll
    for (int j = 0; j < 4; j++) {
        const int col = tx * 4 + j;
        const float bb = vfc_b[col];
#pragma unroll
        for (int i = 0; i < 4; i++)
            vo1s[col][ty * 4 + i] = fmaxf(acc[i][j] + bb, 0.f);
    }

    // ---------------- GEMM1b: ax, K = 128 ----------------
#pragma unroll
    for (int i = 0; i < 4; i++)
#pragma unroll
        for (int j = 0; j < 4; j++) acc[i][j] = 0.f;

    for (int k0 = 0; k0 < 128; k0 += 32) {
        float4 av = *(const float4*)(afeat + (size_t)(r0 + srow) * 128 + k0 + skq * 4);
        const float* wp = afc_w + (size_t)so * 128 + k0 + skh;
        float4 wv[4];
#pragma unroll
        for (int q = 0; q < 4; q++) wv[q] = *(const float4*)(wp + q * 4);

        As[skq * 4 + 0][srow] = av.x; As[skq * 4 + 1][srow] = av.y;
        As[skq * 4 + 2][srow] = av.z; As[skq * 4 + 3][srow] = av.w;
#pragma unroll
        for (int q = 0; q < 4; q++) {
            Bs[skh + q * 4 + 0][so] = wv[q].x;
            Bs[skh + q * 4 + 1][so] = wv[q].y;
            Bs[skh + q * 4 + 2][so] = wv[q].z;
            Bs[skh + q * 4 + 3][so] = wv[q].w;
        }
        __syncthreads();
#pragma unroll
        for (int kk = 0; kk < 32; kk++) {
            float4 a = *(const float4*)&As[kk][ty * 4];
            float4 b = *(const float4*)&Bs[kk][tx * 4];
            fma16(acc, a, b);
        }
        __syncthreads();
    }
#pragma unroll
    for (int j = 0; j < 4; j++) {
        const int col = tx * 4 + j;
        const float bb = afc_b[col];
#pragma unroll
        for (int i = 0; i < 4; i++)
            axs[col][ty * 4 + i] = fmaxf(acc[i][j] + bb, 0.f);
    }

    // ---------------- GEMM2: h = vo1 @ am_v^T + ax @ am_a^T, K = 128 + 128 --
#pragma unroll
    for (int i = 0; i < 4; i++)
#pragma unroll
        for (int j = 0; j < 4; j++) acc[i][j] = 0.f;

    for (int src = 0; src < 2; src++) {
        const float* w = src ? am_a_w : am_v_w;
        const float (*S)[36] = src ? axs : vo1s;
        for (int k0 = 0; k0 < 128; k0 += 32) {
            const float* wp = w + (size_t)so * 128 + k0 + skh;
            float4 wv[4];
#pragma unroll
            for (int q = 0; q < 4; q++) wv[q] = *(const float4*)(wp + q * 4);
#pragma unroll
            for (int q = 0; q < 4; q++) {
                Bs[skh + q * 4 + 0][so] = wv[q].x;
                Bs[skh + q * 4 + 1][so] = wv[q].y;
                Bs[skh + q * 4 + 2][so] = wv[q].z;
                Bs[skh + q * 4 + 3][so] = wv[q].w;
            }
            __syncthreads();
#pragma unroll
            for (int kk = 0; kk < 32; kk++) {
                float4 a = *(const float4*)&S[k0 + kk][ty * 4];
                float4 b = *(const float4*)&Bs[kk][tx * 4];
                fma16(acc, a, b);
            }
            __syncthreads();
        }
    }

    // ---------------- att = sigmoid(tanh(h) . am_o_w + am_o_b) ----------------
    {
        float p0 = 0.f, p1 = 0.f, p2 = 0.f, p3 = 0.f;
#pragma unroll
        for (int j = 0; j < 4; j++) {
            const int col = tx * 4 + j;
            const float bb = am_v_b[col] + am_a_b[col];
            const float wo = am_o_w[col];
            p0 += tanhf(acc[0][j] + bb) * wo;
            p1 += tanhf(acc[1][j] + bb) * wo;
            p2 += tanhf(acc[2][j] + bb) * wo;
            p3 += tanhf(acc[3][j] + bb) * wo;
        }
#pragma unroll
        for (int m = 16; m >= 1; m >>= 1) {
            p0 += __shfl_xor(p0, m);
            p1 += __shfl_xor(p1, m);
            p2 += __shfl_xor(p2, m);
            p3 += __shfl_xor(p3, m);
        }
        if (tx == 0) {
            const float ob = am_o_b[0];
            atts[ty * 4 + 0] = 1.f / (1.f + expf(-(p0 + ob)));
            atts[ty * 4 + 1] = 1.f / (1.f + expf(-(p1 + ob)));
            atts[ty * 4 + 2] = 1.f / (1.f + expf(-(p2 + ob)));
            atts[ty * 4 + 3] = 1.f / (1.f + expf(-(p3 + ob)));
        }
    }
    __syncthreads();

    // ---------------- ffeat = att*ax + vo1 -> global ws ----------------
    {
        const int row = tid >> 3;
        const int kq  = (tid & 7) * 16;
        const float at = atts[row];
        float* op = ffeat_out + (size_t)(r0 + row) * 128 + kq;
#pragma unroll
        for (int q = 0; q < 4; q++) {
            const int k = kq + q * 4;
            float4 f;
            f.x = at * axs[k + 0][row] + vo1s[k + 0][row];
            f.y = at * axs[k + 1][row] + vo1s[k + 1][row];
            f.z = at * axs[k + 2][row] + vo1s[k + 2][row];
            f.w = at * axs[k + 3][row] + vo1s[k + 3][row];
            *(float4*)(op + q * 4) = f;
        }
    }

    // ---------------- GEMM3: f_v = relu(ffeat @ V_w^T + V_b), N=64, K=128 ----
    float acc3[4][2] = {{0.f,0.f},{0.f,0.f},{0.f,0.f},{0.f,0.f}};
    float at4[4];
#pragma unroll
    for (int i = 0; i < 4; i++) at4[i] = atts[ty * 4 + i];

    {
        float* Bsf = &Bs[0][0];                 // reuse as [64][64]
        const int scol = tid >> 2;              // 0..63
        const int skh3 = (tid & 3) * 16;
        for (int k0 = 0; k0 < 128; k0 += 64) {
            const float* wp = V_w + (size_t)scol * 128 + k0 + skh3;
            float4 wv[4];
#pragma unroll
            for (int q = 0; q < 4; q++) wv[q] = *(const float4*)(wp + q * 4);
            __syncthreads();   // everyone done with previous Bs contents
#pragma unroll
            for (int q = 0; q < 4; q++) {
                Bsf[(skh3 + q * 4 + 0) * 64 + scol] = wv[q].x;
                Bsf[(skh3 + q * 4 + 1) * 64 + scol] = wv[q].y;
                Bsf[(skh3 + q * 4 + 2) * 64 + scol] = wv[q].z;
                Bsf[(skh3 + q * 4 + 3) * 64 + scol] = wv[q].w;
            }
            __syncthreads();
#pragma unroll 8
            for (int kk = 0; kk < 64; kk++) {
                const int k = k0 + kk;
                float4 avv = *(const float4*)&axs[k][ty * 4];
                float4 vvv = *(const float4*)&vo1s[k][ty * 4];
                const float a0 = at4[0] * avv.x + vvv.x;
                const float a1 = at4[1] * avv.y + vvv.y;
                const float a2 = at4[2] * avv.z + vvv.z;
                const float a3 = at4[3] * avv.w + vvv.w;
                float2 b = *(const float2*)(Bsf + kk * 64 + tx * 2);
                acc3[0][0] += a0 * b.x; acc3[0][1] += a0 * b.y;
                acc3[1][0] += a1 * b.x; acc3[1][1] += a1 * b.y;
                acc3[2][0] += a2 * b.x; acc3[2][1] += a2 * b.y;
                acc3[3][0] += a3 * b.x; acc3[3][1] += a3 * b.y;
            }
        }
    }

    // ---------------- s = relu(f_v + V_b) . W_w  ->  ws ----------------
    {
        float s0 = 0.f, s1 = 0.f, s2 = 0.f, s3 = 0.f;
#pragma unroll
        for (int j = 0; j < 2; j++) {
            const int col = tx * 2 + j;
            const float vb = V_b[col];
            const float ww = W_w[col];
            s0 += fmaxf(acc3[0][j] + vb, 0.f) * ww;
            s1 += fmaxf(acc3[1][j] + vb, 0.f) * ww;
            s2 += fmaxf(acc3[2][j] + vb, 0.f) * ww;
            s3 += fmaxf(acc3[3][j] + vb, 0.f) * ww;
        }
#pragma unroll
        for (int m = 16; m >= 1; m >>= 1) {
            s0 += __shfl_xor(s0, m);
            s1 += __shfl_xor(s1, m);
            s2 += __shfl_xor(s2, m);
            s3 += __shfl_xor(s3, m);
        }
        if (tx == 0) {
            s_out[r0 + ty * 4 + 0] = s0;
            s_out[r0 + ty * 4 + 1] = s1;
            s_out[r0 + ty * 4 + 2] = s2;
            s_out[r0 + ty * 4 + 3] = s3;
        }
    }
}

// ---------------------------------------------------------------------------
// Phase B: scores = softmax(s) per batch; zfeat = sum_n scores*ffeat; logits.
// ---------------------------------------------------------------------------
__global__ __launch_bounds__(1024)
void milB(const float* __restrict__ s_in, const float* __restrict__ ffeat,
          const float* __restrict__ cls_w, const float* __restrict__ cls_b,
          float* __restrict__ scores_out, float* __restrict__ logits_out)
{
    __shared__ float sh[2048];
    __shared__ float red[16];
    __shared__ float zf[1024];

    const int tid = threadIdx.x;
    const int b   = blockIdx.x;
    const float* sb = s_in + (size_t)b * 2048;

    float v0 = sb[tid], v1 = sb[tid + 1024];
    float mx = fmaxf(v0, v1);
#pragma unroll
    for (int m = 32; m >= 1; m >>= 1) mx = fmaxf(mx, __shfl_xor(mx, m));
    if ((tid & 63) == 0) red[tid >> 6] = mx;
    __syncthreads();
    float bm = red[0];
#pragma unroll
    for (int w = 1; w < 16; w++) bm = fmaxf(bm, red[w]);

    float e0 = expf(v0 - bm), e1 = expf(v1 - bm);
    float sum = e0 + e1;
#pragma unroll
    for (int m = 32; m >= 1; m >>= 1) sum += __shfl_xor(sum, m);
    __syncthreads();                       // all reads of red (max) done
    if ((tid & 63) == 0) red[tid >> 6] = sum;
    __syncthreads();
    float ts = 0.f;
#pragma unroll
    for (int w = 0; w < 16; w++) ts += red[w];
    const float inv = 1.f / ts;

    const float sc0 = e0 * inv, sc1 = e1 * inv;
    sh[tid]        = sc0;
    sh[tid + 1024] = sc1;
    scores_out[(size_t)b * 2048 + tid]        = sc0;
    scores_out[(size_t)b * 2048 + tid + 1024] = sc1;
    __syncthreads();

    // zfeat: 8 n-partitions x 128 feature lanes
    const int k = tid & 127, part = tid >> 7;
    const float* fb = ffeat + ((size_t)b * 2048 + part * 256) * 128 + k;
    const float* sp = sh + part * 256;
    float z = 0.f;
#pragma unroll 8
    for (int n = 0; n < 256; n++) z += sp[n] * fb[(size_t)n * 128];
    zf[tid] = z;
    __syncthreads();
    if (tid < 128) {
        float a = 0.f;
#pragma unroll
        for (int p = 0; p < 8; p++) a += zf[tid + p * 128];
        zf[tid] = a;
    }
    __syncthreads();
    if (tid < 2) {
        float a = cls_b[tid];
        const float* cw = cls_w + tid * 128;
        for (int kk = 0; kk < 128; kk++) a += zf[kk] * cw[kk];
        logits_out[b * 2 + tid] = a;
    }
}

extern "C" void kernel_launch(void* const* d_in, const int* in_sizes, int n_in,
                              void* d_out, int out_size, void* d_ws, size_t ws_size,
                              hipStream_t stream)
{
    (void)in_sizes; (void)n_in; (void)out_size; (void)ws_size;
    const float* vfeat  = (const float*)d_in[0];
    const float* afeat  = (const float*)d_in[1];
    const float* vfc_w  = (const float*)d_in[2];
    const float* vfc_b  = (const float*)d_in[3];
    const float* afc_w  = (const float*)d_in[4];
    const float* afc_b  = (const float*)d_in[5];
    const float* am_v_w = (const float*)d_in[6];
    const float* am_v_b = (const float*)d_in[7];
    const float* am_a_w = (const float*)d_in[8];
    const float* am_a_b = (const float*)d_in[9];
    const float* am_o_w = (const float*)d_in[10];
    const float* am_o_b = (const float*)d_in[11];
    const float* V_w    = (const float*)d_in[12];
    const float* V_b    = (const float*)d_in[13];
    const float* W_w    = (const float*)d_in[14];
    // d_in[15] = W_b: cancels exactly in softmax over axis=1 -> unused.
    const float* cls_w  = (const float*)d_in[16];
    const float* cls_b  = (const float*)d_in[17];

    float* scores = (float*)d_out;
    float* logits = (float*)d_out + 32 * 2048;

    float* ffeat_ws = (float*)d_ws;                       // 65536*128 floats = 32 MB
    float* s_ws     = ffeat_ws + (size_t)65536 * 128;     // 65536 floats

    milA<<<2048, 256, 0, stream>>>(vfeat, afeat, vfc_w, vfc_b, afc_w, afc_b,
                                   am_v_w, am_v_b, am_a_w, am_a_b, am_o_w, am_o_b,
                                   V_w, V_b, W_w, ffeat_ws, s_ws);
    milB<<<32, 1024, 0, stream>>>(s_ws, ffeat_ws, cls_w, cls_b, scores, logits);
}

// Round 4
// 99.260 us; speedup vs baseline: 3.2467x; 3.2467x over previous
//
#include <hip/hip_runtime.h>
#include <cstddef>
#include <cstdint>

// ---------------------------------------------------------------------------
// MILModel7 forward. Exact math simplification: softmax over axis=1 of
// (s_i + s_j + Wb) -> j-terms cancel -> scores = softmax(s, axis=n).
//
// This version moves the GEMM chain to bf16 MFMA (16x16x32):
//  - GEMM1 (vfc, K=512) and GEMM1b (afc, K=128): full hi/lo split-bf16
//    (3 MFMA terms: Ah*Bh + Ah*Bl + Al*Bh) -> ~fp32 accuracy.
//  - GEMM2 (AM, K=256) and GEMM3 (V, K=128): single bf16 (error ~1e-3).
//  - ffeat written in exact f32 from live fp32 accumulators.
// Per-wave fused chain over 32 rows; wave-private LDS; no hot-loop barriers.
// ---------------------------------------------------------------------------

typedef __attribute__((ext_vector_type(8))) short short8;
typedef __attribute__((ext_vector_type(4))) float float4v;

#define MFMA16(a, b, c) __builtin_amdgcn_mfma_f32_16x16x32_bf16((a), (b), (c), 0, 0, 0)

__device__ __forceinline__ unsigned short f2bf(float f) {
    union { float f; unsigned u; } v; v.f = f;
    unsigned r = (v.u + 0x7fffu + ((v.u >> 16) & 1u)) >> 16;
    return (unsigned short)r;
}
__device__ __forceinline__ float bf2f(unsigned short h) {
    union { unsigned u; float f; } v; v.u = ((unsigned)h) << 16;
    return v.f;
}
__device__ __forceinline__ float bf2f_s(short h) { return bf2f((unsigned short)h); }

__device__ __forceinline__ float tanh_fast(float x) {
    // tanh(x) = 1 - 2/(e^{2x}+1);  e^{2x} = 2^{x*2*log2(e)}
    float e = __builtin_exp2f(x * 2.885390081777927f);
    return 1.f - 2.f / (e + 1.f);
}
__device__ __forceinline__ float sigmoid_fast(float x) {
    return 1.f / (1.f + __builtin_exp2f(-x * 1.4426950408889634f));
}

// ---------------------------------------------------------------------------
// prep: split weights into bf16 (hi/lo) MFMA B-fragment layout.
// Frag layout: elem index ((nf*KS + ks)*64 + lane)*8 + j  holds
//   W[n = (lane&15)+16*nf][k = ks*32 + (lane>>4)*8 + j]
// ---------------------------------------------------------------------------
__global__ __launch_bounds__(256)
void prep(const float* __restrict__ vfc_w, const float* __restrict__ afc_w,
          const float* __restrict__ am_v_w, const float* __restrict__ am_a_w,
          const float* __restrict__ V_w,
          unsigned short* __restrict__ W1h, unsigned short* __restrict__ W1l,
          unsigned short* __restrict__ W1bh, unsigned short* __restrict__ W1bl,
          unsigned short* __restrict__ W2v, unsigned short* __restrict__ W2a,
          unsigned short* __restrict__ W3)
{
    int t = blockIdx.x * 256 + threadIdx.x;
    if (t < 65536) {                       // vfc_w (128x512), hi+lo
        int j = t & 7, lane = (t >> 3) & 63, ks = (t >> 9) & 15, nf = (t >> 13) & 7;
        int n = (lane & 15) + 16 * nf, k = ks * 32 + (lane >> 4) * 8 + j;
        float x = vfc_w[n * 512 + k];
        unsigned short h = f2bf(x);
        W1h[t] = h; W1l[t] = f2bf(x - bf2f(h));
    } else if (t < 81920) {                // afc_w (128x128), hi+lo
        int u = t - 65536;
        int j = u & 7, lane = (u >> 3) & 63, ks = (u >> 9) & 3, nf = (u >> 11) & 7;
        int n = (lane & 15) + 16 * nf, k = ks * 32 + (lane >> 4) * 8 + j;
        float x = afc_w[n * 128 + k];
        unsigned short h = f2bf(x);
        W1bh[u] = h; W1bl[u] = f2bf(x - bf2f(h));
    } else if (t < 98304) {                // am_v_w, single
        int u = t - 81920;
        int j = u & 7, lane = (u >> 3) & 63, ks = (u >> 9) & 3, nf = (u >> 11) & 7;
        int n = (lane & 15) + 16 * nf, k = ks * 32 + (lane >> 4) * 8 + j;
        W2v[u] = f2bf(am_v_w[n * 128 + k]);
    } else if (t < 114688) {               // am_a_w, single
        int u = t - 98304;
        int j = u & 7, lane = (u >> 3) & 63, ks = (u >> 9) & 3, nf = (u >> 11) & 7;
        int n = (lane & 15) + 16 * nf, k = ks * 32 + (lane >> 4) * 8 + j;
        W2a[u] = f2bf(am_a_w[n * 128 + k]);
    } else if (t < 122880) {               // V_w (64x128), single
        int u = t - 114688;
        int j = u & 7, lane = (u >> 3) & 63, ks = (u >> 9) & 3, nf = (u >> 11) & 3;
        int n = (lane & 15) + 16 * nf, k = ks * 32 + (lane >> 4) * 8 + j;
        W3[u] = f2bf(V_w[n * 128 + k]);
    }
}

// ---------------------------------------------------------------------------
// milA: fused per-wave chain. 4 waves/block, 32 rows/wave, grid 512.
// ---------------------------------------------------------------------------
__global__ __launch_bounds__(256, 2)
void milA(const float* __restrict__ vfeat, const float* __restrict__ afeat,
          const float* __restrict__ vfc_b, const float* __restrict__ afc_b,
          const float* __restrict__ am_v_b, const float* __restrict__ am_a_b,
          const float* __restrict__ am_o_w, const float* __restrict__ am_o_b,
          const float* __restrict__ V_b, const float* __restrict__ W_w,
          const unsigned short* __restrict__ W1h, const unsigned short* __restrict__ W1l,
          const unsigned short* __restrict__ W1bh, const unsigned short* __restrict__ W1bl,
          const unsigned short* __restrict__ W2v, const unsigned short* __restrict__ W2a,
          const unsigned short* __restrict__ W3,
          float* __restrict__ ffeat_out, float* __restrict__ s_out)
{
    __shared__ unsigned short vo1s[4][32][136];   // bf16, padded (+8) rows
    __shared__ unsigned short axs[4][32][136];
    __shared__ float atts[4][32];

    const int tid = threadIdx.x;
    const int lane = tid & 63, wid = tid >> 6;
    const int lr = lane & 15, lg = lane >> 4;
    const int row0 = blockIdx.x * 128 + wid * 32;   // flat row base (b*2048+n)

    // ---- preload per-lane bias/weight scalars --------------------------------
    float b1[8], b1b[8], bias2[8], wo[8];
#pragma unroll
    for (int nf = 0; nf < 8; ++nf) {
        const int c = lr + 16 * nf;
        b1[nf] = vfc_b[c];
        b1b[nf] = afc_b[c];
        bias2[nf] = am_v_b[c] + am_a_b[c];
        wo[nf] = am_o_w[c];
    }
    const float ob = am_o_b[0];

    // ================= GEMM1: vo1 = relu(vfeat @ vfc^T + b), K=512 ============
    float4v acc1[2][8];
#pragma unroll
    for (int rf = 0; rf < 2; ++rf)
#pragma unroll
        for (int nf = 0; nf < 8; ++nf)
#pragma unroll
            for (int i = 0; i < 4; ++i) acc1[rf][nf][i] = 0.f;

    for (int ks = 0; ks < 16; ++ks) {
        short8 ah[2], al[2];
#pragma unroll
        for (int rf = 0; rf < 2; ++rf) {
            const float* ap = vfeat + (size_t)(row0 + rf * 16 + lr) * 512 + ks * 32 + lg * 8;
            float4 x0 = *(const float4*)ap;
            float4 x1 = *(const float4*)(ap + 4);
            float xs[8] = {x0.x, x0.y, x0.z, x0.w, x1.x, x1.y, x1.z, x1.w};
#pragma unroll
            for (int j = 0; j < 8; ++j) {
                unsigned short h = f2bf(xs[j]);
                ah[rf][j] = (short)h;
                al[rf][j] = (short)f2bf(xs[j] - bf2f(h));
            }
        }
#pragma unroll
        for (int nf = 0; nf < 8; ++nf) {
            const short8 bh = *(const short8*)(W1h + ((size_t)(nf * 16 + ks) * 64 + lane) * 8);
            const short8 bl = *(const short8*)(W1l + ((size_t)(nf * 16 + ks) * 64 + lane) * 8);
#pragma unroll
            for (int rf = 0; rf < 2; ++rf) {
                acc1[rf][nf] = MFMA16(ah[rf], bh, acc1[rf][nf]);
                acc1[rf][nf] = MFMA16(ah[rf], bl, acc1[rf][nf]);
                acc1[rf][nf] = MFMA16(al[rf], bh, acc1[rf][nf]);
            }
        }
    }
    // epilogue: bias+relu (keep exact f32 in acc1), bf16 copy to LDS
#pragma unroll
    for (int rf = 0; rf < 2; ++rf)
#pragma unroll
        for (int nf = 0; nf < 8; ++nf)
#pragma unroll
            for (int r = 0; r < 4; ++r) {
                float v = fmaxf(acc1[rf][nf][r] + b1[nf], 0.f);
                acc1[rf][nf][r] = v;
                vo1s[wid][rf * 16 + lg * 4 + r][lr + 16 * nf] = f2bf(v);
            }

    // ================= GEMM1b: ax = relu(afeat @ afc^T + b), K=128 ============
    float4v acc1b[2][8];
#pragma unroll
    for (int rf = 0; rf < 2; ++rf)
#pragma unroll
        for (int nf = 0; nf < 8; ++nf)
#pragma unroll
            for (int i = 0; i < 4; ++i) acc1b[rf][nf][i] = 0.f;

    for (int ks = 0; ks < 4; ++ks) {
        short8 ah[2], al[2];
#pragma unroll
        for (int rf = 0; rf < 2; ++rf) {
            const float* ap = afeat + (size_t)(row0 + rf * 16 + lr) * 128 + ks * 32 + lg * 8;
            float4 x0 = *(const float4*)ap;
            float4 x1 = *(const float4*)(ap + 4);
            float xs[8] = {x0.x, x0.y, x0.z, x0.w, x1.x, x1.y, x1.z, x1.w};
#pragma unroll
            for (int j = 0; j < 8; ++j) {
                unsigned short h = f2bf(xs[j]);
                ah[rf][j] = (short)h;
                al[rf][j] = (short)f2bf(xs[j] - bf2f(h));
            }
        }
#pragma unroll
        for (int nf = 0; nf < 8; ++nf) {
            const short8 bh = *(const short8*)(W1bh + ((size_t)(nf * 4 + ks) * 64 + lane) * 8);
            const short8 bl = *(const short8*)(W1bl + ((size_t)(nf * 4 + ks) * 64 + lane) * 8);
#pragma unroll
            for (int rf = 0; rf < 2; ++rf) {
                acc1b[rf][nf] = MFMA16(ah[rf], bh, acc1b[rf][nf]);
                acc1b[rf][nf] = MFMA16(ah[rf], bl, acc1b[rf][nf]);
                acc1b[rf][nf] = MFMA16(al[rf], bh, acc1b[rf][nf]);
            }
        }
    }
#pragma unroll
    for (int rf = 0; rf < 2; ++rf)
#pragma unroll
        for (int nf = 0; nf < 8; ++nf)
#pragma unroll
            for (int r = 0; r < 4; ++r) {
                float v = fmaxf(acc1b[rf][nf][r] + b1b[nf], 0.f);
                acc1b[rf][nf][r] = v;
                axs[wid][rf * 16 + lg * 4 + r][lr + 16 * nf] = f2bf(v);
            }

    __syncthreads();   // LDS vo1s/axs writes -> reads

    // ================= GEMM2: h = vo1 @ am_v^T + ax @ am_a^T (single bf16) ====
    float4v acc2[2][8];
#pragma unroll
    for (int rf = 0; rf < 2; ++rf)
#pragma unroll
        for (int nf = 0; nf < 8; ++nf)
#pragma unroll
            for (int i = 0; i < 4; ++i) acc2[rf][nf][i] = 0.f;

#pragma unroll
    for (int ks = 0; ks < 4; ++ks) {
        short8 a2[2];
#pragma unroll
        for (int rf = 0; rf < 2; ++rf)
            a2[rf] = *(const short8*)&vo1s[wid][rf * 16 + lr][ks * 32 + lg * 8];
#pragma unroll
        for (int nf = 0; nf < 8; ++nf) {
            const short8 b = *(const short8*)(W2v + ((size_t)(nf * 4 + ks) * 64 + lane) * 8);
#pragma unroll
            for (int rf = 0; rf < 2; ++rf) acc2[rf][nf] = MFMA16(a2[rf], b, acc2[rf][nf]);
        }
    }
#pragma unroll
    for (int ks = 0; ks < 4; ++ks) {
        short8 a2[2];
#pragma unroll
        for (int rf = 0; rf < 2; ++rf)
            a2[rf] = *(const short8*)&axs[wid][rf * 16 + lr][ks * 32 + lg * 8];
#pragma unroll
        for (int nf = 0; nf < 8; ++nf) {
            const short8 b = *(const short8*)(W2a + ((size_t)(nf * 4 + ks) * 64 + lane) * 8);
#pragma unroll
            for (int rf = 0; rf < 2; ++rf) acc2[rf][nf] = MFMA16(a2[rf], b, acc2[rf][nf]);
        }
    }

    // ---- att = sigmoid(tanh(h).am_o + ob), per row ---------------------------
    float attc[2][4];
#pragma unroll
    for (int rf = 0; rf < 2; ++rf)
#pragma unroll
        for (int r = 0; r < 4; ++r) {
            float p = 0.f;
#pragma unroll
            for (int nf = 0; nf < 8; ++nf)
                p += tanh_fast(acc2[rf][nf][r] + bias2[nf]) * wo[nf];
            p += __shfl_xor(p, 1);
            p += __shfl_xor(p, 2);
            p += __shfl_xor(p, 4);
            p += __shfl_xor(p, 8);
            attc[rf][r] = sigmoid_fast(p + ob);
        }
    if (lr == 0) {
#pragma unroll
        for (int rf = 0; rf < 2; ++rf)
#pragma unroll
            for (int r = 0; r < 4; ++r)
                atts[wid][rf * 16 + lg * 4 + r] = attc[rf][r];
    }

    // ---- ffeat = att*ax + vo1 (exact f32 from live accs) -> global -----------
#pragma unroll
    for (int rf = 0; rf < 2; ++rf)
#pragma unroll
        for (int nf = 0; nf < 8; ++nf)
#pragma unroll
            for (int r = 0; r < 4; ++r)
                ffeat_out[(size_t)(row0 + rf * 16 + lg * 4 + r) * 128 + lr + 16 * nf] =
                    attc[rf][r] * acc1b[rf][nf][r] + acc1[rf][nf][r];

    __syncthreads();   // atts visible

    float attv[2];
#pragma unroll
    for (int rf = 0; rf < 2; ++rf) attv[rf] = atts[wid][rf * 16 + lr];

    // ================= GEMM3: f_v = relu(ffeat @ V^T + Vb), N=64 ==============
    float4v acc3[2][4];
#pragma unroll
    for (int rf = 0; rf < 2; ++rf)
#pragma unroll
        for (int nf = 0; nf < 4; ++nf)
#pragma unroll
            for (int i = 0; i < 4; ++i) acc3[rf][nf][i] = 0.f;

#pragma unroll
    for (int ks = 0; ks < 4; ++ks) {
        short8 a3[2];
#pragma unroll
        for (int rf = 0; rf < 2; ++rf) {
            const short8 x8 = *(const short8*)&axs[wid][rf * 16 + lr][ks * 32 + lg * 8];
            const short8 v8 = *(const short8*)&vo1s[wid][rf * 16 + lr][ks * 32 + lg * 8];
#pragma unroll
            for (int j = 0; j < 8; ++j) {
                float f = attv[rf] * bf2f_s(x8[j]) + bf2f_s(v8[j]);
                a3[rf][j] = (short)f2bf(f);
            }
        }
#pragma unroll
        for (int nf = 0; nf < 4; ++nf) {
            const short8 b = *(const short8*)(W3 + ((size_t)(nf * 4 + ks) * 64 + lane) * 8);
#pragma unroll
            for (int rf = 0; rf < 2; ++rf) acc3[rf][nf] = MFMA16(a3[rf], b, acc3[rf][nf]);
        }
    }

    // ---- s = relu(f_v + V_b) . W_w -> ws -------------------------------------
    float vb3[4], ww3[4];
#pragma unroll
    for (int nf = 0; nf < 4; ++nf) {
        const int c = lr + 16 * nf;
        vb3[nf] = V_b[c];
        ww3[nf] = W_w[c];
    }
#pragma unroll
    for (int rf = 0; rf < 2; ++rf)
#pragma unroll
        for (int r = 0; r < 4; ++r) {
            float q = 0.f;
#pragma unroll
            for (int nf = 0; nf < 4; ++nf)
                q += fmaxf(acc3[rf][nf][r] + vb3[nf], 0.f) * ww3[nf];
            q += __shfl_xor(q, 1);
            q += __shfl_xor(q, 2);
            q += __shfl_xor(q, 4);
            q += __shfl_xor(q, 8);
            if (lr == 0) s_out[row0 + rf * 16 + lg * 4 + r] = q;
        }
}

// ---------------------------------------------------------------------------
// Phase B
// ---------------------------------------------------------------------------
__device__ __forceinline__ float wred_sum(float v) {
#pragma unroll
    for (int m = 32; m >= 1; m >>= 1) v += __shfl_xor(v, m);
    return v;
}
__device__ __forceinline__ float wred_max(float v) {
#pragma unroll
    for (int m = 32; m >= 1; m >>= 1) v = fmaxf(v, __shfl_xor(v, m));
    return v;
}

__global__ __launch_bounds__(256)
void milB1(const float* __restrict__ s_in, float* __restrict__ scores_out)
{
    __shared__ float red[4];
    const int t = threadIdx.x, b = blockIdx.x, w = t >> 6;
    const float* sb = s_in + (size_t)b * 2048;

    float v[8];
#pragma unroll
    for (int q = 0; q < 8; ++q) v[q] = sb[q * 256 + t];
    float m = v[0];
#pragma unroll
    for (int q = 1; q < 8; ++q) m = fmaxf(m, v[q]);
    m = wred_max(m);
    if ((t & 63) == 0) red[w] = m;
    __syncthreads();
    const float bm = fmaxf(fmaxf(red[0], red[1]), fmaxf(red[2], red[3]));

    float e[8], sum = 0.f;
#pragma unroll
    for (int q = 0; q < 8; ++q) { e[q] = expf(v[q] - bm); sum += e[q]; }
    sum = wred_sum(sum);
    __syncthreads();
    if ((t & 63) == 0) red[w] = sum;
    __syncthreads();
    const float inv = 1.f / (red[0] + red[1] + red[2] + red[3]);
#pragma unroll
    for (int q = 0; q < 8; ++q)
        scores_out[(size_t)b * 2048 + q * 256 + t] = e[q] * inv;
}

__global__ __launch_bounds__(256)
void milB2(const float* __restrict__ scores, const float* __restrict__ ffeat,
           float* __restrict__ parts)
{
    __shared__ float sh[256];
    __shared__ float zbuf[256];
    const int t = threadIdx.x;
    const int b = blockIdx.x >> 3, part = blockIdx.x & 7;
    const int col = t & 127, half = t >> 7;

    sh[t] = scores[(size_t)b * 2048 + part * 256 + t];
    __syncthreads();

    const float* fb = ffeat + ((size_t)(b * 2048 + part * 256 + half * 128)) * 128 + col;
    const float* sp = sh + half * 128;
    float z = 0.f;
#pragma unroll 8
    for (int nn = 0; nn < 128; ++nn) z += sp[nn] * fb[(size_t)nn * 128];
    zbuf[t] = z;
    __syncthreads();
    if (t < 128) parts[((size_t)(b * 8 + part)) * 128 + t] = zbuf[t] + zbuf[t + 128];
}

__global__ __launch_bounds__(128)
void milB3(const float* __restrict__ parts, const float* __restrict__ cls_w,
           const float* __restrict__ cls_b, float* __restrict__ logits)
{
    __shared__ float zfs[128];
    const int t = threadIdx.x, b = blockIdx.x;
    float zf = 0.f;
#pragma unroll
    for (int p = 0; p < 8; ++p) zf += parts[((size_t)(b * 8 + p)) * 128 + t];
    zfs[t] = zf;
    __syncthreads();
    const int o = t >> 6, c = t & 63;
    float q = zfs[c] * cls_w[o * 128 + c] + zfs[c + 64] * cls_w[o * 128 + c + 64];
    q = wred_sum(q);
    if (c == 0) logits[b * 2 + o] = q + cls_b[o];
}

extern "C" void kernel_launch(void* const* d_in, const int* in_sizes, int n_in,
                              void* d_out, int out_size, void* d_ws, size_t ws_size,
                              hipStream_t stream)
{
    (void)in_sizes; (void)n_in; (void)out_size; (void)ws_size;
    const float* vfeat  = (const float*)d_in[0];
    const float* afeat  = (const float*)d_in[1];
    const float* vfc_w  = (const float*)d_in[2];
    const float* vfc_b  = (const float*)d_in[3];
    const float* afc_w  = (const float*)d_in[4];
    const float* afc_b  = (const float*)d_in[5];
    const float* am_v_w = (const float*)d_in[6];
    const float* am_v_b = (const float*)d_in[7];
    const float* am_a_w = (const float*)d_in[8];
    const float* am_a_b = (const float*)d_in[9];
    const float* am_o_w = (const float*)d_in[10];
    const float* am_o_b = (const float*)d_in[11];
    const float* V_w    = (const float*)d_in[12];
    const float* V_b    = (const float*)d_in[13];
    const float* W_w    = (const float*)d_in[14];
    // d_in[15] = W_b: cancels exactly in the softmax over axis=1 -> unused.
    const float* cls_w  = (const float*)d_in[16];
    const float* cls_b  = (const float*)d_in[17];

    float* scores = (float*)d_out;                 // 32*2048
    float* logits = (float*)d_out + 32 * 2048;     // 32*2

    char* ws = (char*)d_ws;
    float* ffeat_ws = (float*)ws;                              // 33,554,432 B
    float* s_ws     = (float*)(ws + 33554432);                 //    262,144 B
    float* parts_ws = (float*)(ws + 33816576);                 //    131,072 B
    unsigned short* W1h  = (unsigned short*)(ws + 33947648);   // 65536
    unsigned short* W1l  = W1h + 65536;
    unsigned short* W1bh = W1l + 65536;                        // 16384
    unsigned short* W1bl = W1bh + 16384;
    unsigned short* W2v  = W1bl + 16384;
    unsigned short* W2a  = W2v + 16384;
    unsigned short* W3   = W2a + 16384;                        // 8192; end ~34.4 MB

    prep<<<480, 256, 0, stream>>>(vfc_w, afc_w, am_v_w, am_a_w, V_w,
                                  W1h, W1l, W1bh, W1bl, W2v, W2a, W3);
    milA<<<512, 256, 0, stream>>>(vfeat, afeat, vfc_b, afc_b, am_v_b, am_a_b,
                                  am_o_w, am_o_b, V_b, W_w,
                                  W1h, W1l, W1bh, W1bl, W2v, W2a, W3,
                                  ffeat_ws, s_ws);
    milB1<<<32, 256, 0, stream>>>(s_ws, scores);
    milB2<<<256, 256, 0, stream>>>(scores, ffeat_ws, parts_ws);
    milB3<<<32, 128, 0, stream>>>(parts_ws, cls_w, cls_b, logits);
}